// Round 1
// baseline (239.268 us; speedup 1.0000x reference)
//
#include <hip/hip_runtime.h>

// Problem constants (from reference): org/enh [32,3,512,512] fp32.
#define NB 32
#define NC 3
#define NH 512
#define NW 512
#define PH 128   // NH/4
#define PW 128   // NW/4
#define NPOOL (NB * PH * PW)  // 524288 pooled elements (2 MB fp32)

// Kernel 1: fused channel-mean + 4x4 avgpool + (org - enh).
// One thread per pooled output element. Each float4 load spans exactly one
// pooled column (pool width 4 == float4), so lane i reads base + 16*i:
// fully coalesced 1 KB/wave per instruction. 24 dwordx4 loads + 1 store/thread.
__global__ __launch_bounds__(256) void pool_diff_kernel(
    const float* __restrict__ org, const float* __restrict__ enh,
    float* __restrict__ pooled)
{
    int idx = blockIdx.x * blockDim.x + threadIdx.x;  // 0..NPOOL-1
    int pw = idx & (PW - 1);
    int ph = (idx >> 7) & (PH - 1);
    int b  = idx >> 14;

    const float4* o4 = (const float4*)org;
    const float4* e4 = (const float4*)enh;
    const int rowF4 = NW / 4;  // 128 float4s per image row

    float acc = 0.f;
#pragma unroll
    for (int c = 0; c < NC; ++c) {
        int base = ((b * NC + c) * NH + 4 * ph) * rowF4 + pw;
#pragma unroll
        for (int dy = 0; dy < 4; ++dy) {
            float4 o = o4[base + dy * rowF4];
            float4 e = e4[base + dy * rowF4];
            acc += (o.x - e.x) + (o.y - e.y) + (o.z - e.z) + (o.w - e.w);
        }
    }
    pooled[idx] = acc * (1.0f / 48.0f);  // /3 channels /16 pool window
}

// Kernel 2: shift-difference sum-of-squares + global mean reduction.
// d_left = c - left, etc., zero-padded per 128x128 image. 2 MB input is
// L2-resident. Wave shuffle reduce -> LDS -> one atomicAdd per block.
__global__ __launch_bounds__(256) void spa_reduce_kernel(
    const float* __restrict__ pooled, float* __restrict__ out)
{
    int idx = blockIdx.x * blockDim.x + threadIdx.x;
    int pw = idx & (PW - 1);
    int ph = (idx >> 7) & (PH - 1);
    int b  = idx >> 14;
    const float* img = pooled + b * (PH * PW);

    float c = img[ph * PW + pw];
    float l = (pw > 0)      ? img[ph * PW + pw - 1] : 0.f;
    float r = (pw < PW - 1) ? img[ph * PW + pw + 1] : 0.f;
    float u = (ph > 0)      ? img[(ph - 1) * PW + pw] : 0.f;
    float d = (ph < PH - 1) ? img[(ph + 1) * PW + pw] : 0.f;

    float dl = c - l, dr = c - r, du = c - u, dd = c - d;
    float s = dl * dl + dr * dr + du * du + dd * dd;

    // wave-64 butterfly reduce
#pragma unroll
    for (int off = 32; off > 0; off >>= 1)
        s += __shfl_down(s, off, 64);

    __shared__ float smem[4];  // 256 threads = 4 waves
    int lane = threadIdx.x & 63;
    int wid  = threadIdx.x >> 6;
    if (lane == 0) smem[wid] = s;
    __syncthreads();
    if (threadIdx.x == 0) {
        float t = smem[0] + smem[1] + smem[2] + smem[3];
        atomicAdd(out, t * (1.0f / (float)NPOOL));
    }
}

extern "C" void kernel_launch(void* const* d_in, const int* in_sizes, int n_in,
                              void* d_out, int out_size, void* d_ws, size_t ws_size,
                              hipStream_t stream) {
    const float* org = (const float*)d_in[0];
    const float* enh = (const float*)d_in[1];
    float* out = (float*)d_out;
    float* pooled = (float*)d_ws;  // needs NPOOL*4 = 2 MB scratch

    // d_out is poisoned 0xAA before every launch; zero it (async, capture-safe)
    hipMemsetAsync(out, 0, sizeof(float), stream);

    pool_diff_kernel<<<NPOOL / 256, 256, 0, stream>>>(org, enh, pooled);
    spa_reduce_kernel<<<NPOOL / 256, 256, 0, stream>>>(pooled, out);
}

// Round 2
// 215.673 us; speedup vs baseline: 1.1094x; 1.1094x over previous
//
#include <hip/hip_runtime.h>

// Problem constants (from reference): org/enh [32,3,512,512] fp32.
#define NB 32
#define NC 3
#define NH 512
#define NW 512
#define PH 128   // NH/4
#define PW 128   // NW/4
#define NPOOL (NB * PH * PW)      // 524288 pooled elements (2 MB fp32)
#define NBLK_POOL (NPOOL / 256)   // 2048 blocks
#define NBLK_RED  (NPOOL / 256)   // 2048 partials

// Kernel 1: fused channel-mean + 4x4 avgpool + (org - enh).
// One thread per pooled element. All 24 float4 loads issued upfront into
// register arrays (~120 VGPRs -> 4 waves/SIMD but 48 loads in flight per
// wave), 4 independent accumulator chains. Each float4 spans exactly one
// pooled column; lane i reads base+16i -> fully coalesced 1 KB/wave/instr.
__global__ __launch_bounds__(256) void pool_diff_kernel(
    const float* __restrict__ org, const float* __restrict__ enh,
    float* __restrict__ pooled)
{
    int idx = blockIdx.x * blockDim.x + threadIdx.x;  // 0..NPOOL-1
    int pw = idx & (PW - 1);
    int ph = (idx >> 7) & (PH - 1);
    int b  = idx >> 14;

    const float4* o4 = (const float4*)org;
    const float4* e4 = (const float4*)enh;
    const int rowF4 = NW / 4;              // 128 float4 per image row
    const int chanF4 = NH * rowF4;         // 65536 float4 per channel

    int base = (b * NC * NH + 4 * ph) * rowF4 + pw;

    float4 o[12], e[12];
#pragma unroll
    for (int c = 0; c < NC; ++c) {
#pragma unroll
        for (int dy = 0; dy < 4; ++dy) {
            int off = base + c * chanF4 + dy * rowF4;
            o[c * 4 + dy] = o4[off];
            e[c * 4 + dy] = e4[off];
        }
    }

    // 4 independent accumulator chains (3 adds each), then combine.
    float4 a0, a1, a2, a3;
    a0.x = o[0].x - e[0].x; a0.y = o[0].y - e[0].y; a0.z = o[0].z - e[0].z; a0.w = o[0].w - e[0].w;
    a1.x = o[1].x - e[1].x; a1.y = o[1].y - e[1].y; a1.z = o[1].z - e[1].z; a1.w = o[1].w - e[1].w;
    a2.x = o[2].x - e[2].x; a2.y = o[2].y - e[2].y; a2.z = o[2].z - e[2].z; a2.w = o[2].w - e[2].w;
    a3.x = o[3].x - e[3].x; a3.y = o[3].y - e[3].y; a3.z = o[3].z - e[3].z; a3.w = o[3].w - e[3].w;
#pragma unroll
    for (int i = 4; i < 12; i += 4) {
        a0.x += o[i].x - e[i].x;     a0.y += o[i].y - e[i].y;     a0.z += o[i].z - e[i].z;     a0.w += o[i].w - e[i].w;
        a1.x += o[i+1].x - e[i+1].x; a1.y += o[i+1].y - e[i+1].y; a1.z += o[i+1].z - e[i+1].z; a1.w += o[i+1].w - e[i+1].w;
        a2.x += o[i+2].x - e[i+2].x; a2.y += o[i+2].y - e[i+2].y; a2.z += o[i+2].z - e[i+2].z; a2.w += o[i+2].w - e[i+2].w;
        a3.x += o[i+3].x - e[i+3].x; a3.y += o[i+3].y - e[i+3].y; a3.z += o[i+3].z - e[i+3].z; a3.w += o[i+3].w - e[i+3].w;
    }
    float acc = ((a0.x + a1.x) + (a2.x + a3.x)) + ((a0.y + a1.y) + (a2.y + a3.y))
              + ((a0.z + a1.z) + (a2.z + a3.z)) + ((a0.w + a1.w) + (a2.w + a3.w));

    pooled[idx] = acc * (1.0f / 48.0f);  // /3 channels /16 pool window
}

// Kernel 2: shift-difference sum-of-squares; per-block partial sums to ws
// (NO single-address atomics — 2048 atomics to one line ping-pong across
// 8 non-coherent XCD L2s and serialize).
__global__ __launch_bounds__(256) void spa_reduce_kernel(
    const float* __restrict__ pooled, float* __restrict__ partials)
{
    int idx = blockIdx.x * blockDim.x + threadIdx.x;
    int pw = idx & (PW - 1);
    int ph = (idx >> 7) & (PH - 1);
    int b  = idx >> 14;
    const float* img = pooled + b * (PH * PW);

    float c = img[ph * PW + pw];
    float l = (pw > 0)      ? img[ph * PW + pw - 1] : 0.f;
    float r = (pw < PW - 1) ? img[ph * PW + pw + 1] : 0.f;
    float u = (ph > 0)      ? img[(ph - 1) * PW + pw] : 0.f;
    float d = (ph < PH - 1) ? img[(ph + 1) * PW + pw] : 0.f;

    float dl = c - l, dr = c - r, du = c - u, dd = c - d;
    float s = (dl * dl + dr * dr) + (du * du + dd * dd);

#pragma unroll
    for (int off = 32; off > 0; off >>= 1)
        s += __shfl_down(s, off, 64);

    __shared__ float smem[4];
    int lane = threadIdx.x & 63;
    int wid  = threadIdx.x >> 6;
    if (lane == 0) smem[wid] = s;
    __syncthreads();
    if (threadIdx.x == 0)
        partials[blockIdx.x] = (smem[0] + smem[1]) + (smem[2] + smem[3]);
}

// Kernel 3: single block folds 2048 partials -> final mean. Writes d_out
// directly (no memset needed).
__global__ __launch_bounds__(256) void final_reduce_kernel(
    const float* __restrict__ partials, float* __restrict__ out)
{
    float s = 0.f;
#pragma unroll
    for (int i = 0; i < NBLK_RED / 256; ++i)
        s += partials[i * 256 + threadIdx.x];

#pragma unroll
    for (int off = 32; off > 0; off >>= 1)
        s += __shfl_down(s, off, 64);

    __shared__ float smem[4];
    int lane = threadIdx.x & 63;
    int wid  = threadIdx.x >> 6;
    if (lane == 0) smem[wid] = s;
    __syncthreads();
    if (threadIdx.x == 0)
        out[0] = ((smem[0] + smem[1]) + (smem[2] + smem[3])) * (1.0f / (float)NPOOL);
}

extern "C" void kernel_launch(void* const* d_in, const int* in_sizes, int n_in,
                              void* d_out, int out_size, void* d_ws, size_t ws_size,
                              hipStream_t stream) {
    const float* org = (const float*)d_in[0];
    const float* enh = (const float*)d_in[1];
    float* out = (float*)d_out;
    float* pooled   = (float*)d_ws;                       // 2 MB
    float* partials = (float*)d_ws + NPOOL;               // + 8 KB

    pool_diff_kernel<<<NBLK_POOL, 256, 0, stream>>>(org, enh, pooled);
    spa_reduce_kernel<<<NBLK_RED, 256, 0, stream>>>(pooled, partials);
    final_reduce_kernel<<<1, 256, 0, stream>>>(partials, out);
}

// Round 3
// 213.672 us; speedup vs baseline: 1.1198x; 1.0094x over previous
//
#include <hip/hip_runtime.h>

// Problem constants (from reference): org/enh [32,3,512,512] fp32.
#define NB 32
#define NC 3
#define NH 512
#define NW 512
#define PH 128   // NH/4
#define PW 128   // NW/4
#define NPOOL  (NB * PH * PW)     // 524288 pooled elements
#define NPLANE (NB * NC)          // 96 (b,c) planes
#define PLANE_ELEMS (PH * PW)     // 16384 per partial plane
#define NBLK_A (NPLANE * NH / 8)  // 6144 blocks: 8 image rows each
#define NBLK_RED (NPOOL / 256)    // 2048

// Stage A: per-channel fused 4x4 avgpool column+row sum of (org - enh).
// Block n reads ONE contiguous 16 KB chunk from each input (8 consecutive
// image rows of one (b,c) plane) -> the whole grid is two linear sweeps,
// same address behavior as the 6.3 TB/s float4 copy (page/TLB-local, no
// scattered streams). Thread = (ph_local in {0,1}, x4): 4 row-strided
// float4 loads per array, horizontal sum within float4 = pool width.
// Writes per-channel partial planes [96][128][128] to ws (6 MB).
__global__ __launch_bounds__(256) void stageA_pool_kernel(
    const float4* __restrict__ o4, const float4* __restrict__ e4,
    float* __restrict__ partial)
{
    int t   = threadIdx.x;
    int x4  = t & 127;        // pooled column
    int phl = t >> 7;         // 0/1: which 4-row half of the 8-row chunk
    int base = blockIdx.x * 1024 + phl * 512 + x4;  // float4 index

    float4 o0 = o4[base];
    float4 o1 = o4[base + 128];
    float4 o2 = o4[base + 256];
    float4 o3 = o4[base + 384];
    float4 e0 = e4[base];
    float4 e1 = e4[base + 128];
    float4 e2 = e4[base + 256];
    float4 e3 = e4[base + 384];

    float4 d;
    d.x = ((o0.x - e0.x) + (o1.x - e1.x)) + ((o2.x - e2.x) + (o3.x - e3.x));
    d.y = ((o0.y - e0.y) + (o1.y - e1.y)) + ((o2.y - e2.y) + (o3.y - e3.y));
    d.z = ((o0.z - e0.z) + (o1.z - e1.z)) + ((o2.z - e2.z) + (o3.z - e3.z));
    d.w = ((o0.w - e0.w) + (o1.w - e1.w)) + ((o2.w - e2.w) + (o3.w - e3.w));
    float v = (d.x + d.y) + (d.z + d.w);

    int plane = blockIdx.x >> 6;                  // (b,c) plane 0..95
    int prow  = ((blockIdx.x & 63) << 1) | phl;   // pooled row 0..127
    partial[plane * PLANE_ELEMS + prow * PW + x4] = v * (1.0f / 48.0f);
}

// Stage B: shift-difference sum-of-squares with inline channel-plane sum.
// pooled[b,y,x] = sum_c partial[(3b+c),y,x]; reads are L2/L3-resident
// (6 MB working set). Per-block partials to ws (no single-address atomics).
__global__ __launch_bounds__(256) void spa_reduce_kernel(
    const float* __restrict__ partial, float* __restrict__ partials_out)
{
    int idx = blockIdx.x * blockDim.x + threadIdx.x;
    int pw = idx & (PW - 1);
    int ph = (idx >> 7) & (PH - 1);
    int b  = idx >> 14;

    const float* p0 = partial + (b * 3 + 0) * PLANE_ELEMS;
    const float* p1 = partial + (b * 3 + 1) * PLANE_ELEMS;
    const float* p2 = partial + (b * 3 + 2) * PLANE_ELEMS;

    #define POOLED(y, x) (p0[(y) * PW + (x)] + p1[(y) * PW + (x)] + p2[(y) * PW + (x)])
    float c = POOLED(ph, pw);
    float l = (pw > 0)      ? POOLED(ph, pw - 1) : 0.f;
    float r = (pw < PW - 1) ? POOLED(ph, pw + 1) : 0.f;
    float u = (ph > 0)      ? POOLED(ph - 1, pw) : 0.f;
    float d = (ph < PH - 1) ? POOLED(ph + 1, pw) : 0.f;
    #undef POOLED

    float dl = c - l, dr = c - r, du = c - u, dd = c - d;
    float s = (dl * dl + dr * dr) + (du * du + dd * dd);

#pragma unroll
    for (int off = 32; off > 0; off >>= 1)
        s += __shfl_down(s, off, 64);

    __shared__ float smem[4];
    int lane = threadIdx.x & 63;
    int wid  = threadIdx.x >> 6;
    if (lane == 0) smem[wid] = s;
    __syncthreads();
    if (threadIdx.x == 0)
        partials_out[blockIdx.x] = (smem[0] + smem[1]) + (smem[2] + smem[3]);
}

// Stage C: single block folds 2048 partials -> final mean, writes d_out.
__global__ __launch_bounds__(256) void final_reduce_kernel(
    const float* __restrict__ partials, float* __restrict__ out)
{
    float s = 0.f;
#pragma unroll
    for (int i = 0; i < NBLK_RED / 256; ++i)
        s += partials[i * 256 + threadIdx.x];

#pragma unroll
    for (int off = 32; off > 0; off >>= 1)
        s += __shfl_down(s, off, 64);

    __shared__ float smem[4];
    int lane = threadIdx.x & 63;
    int wid  = threadIdx.x >> 6;
    if (lane == 0) smem[wid] = s;
    __syncthreads();
    if (threadIdx.x == 0)
        out[0] = ((smem[0] + smem[1]) + (smem[2] + smem[3])) * (1.0f / (float)NPOOL);
}

extern "C" void kernel_launch(void* const* d_in, const int* in_sizes, int n_in,
                              void* d_out, int out_size, void* d_ws, size_t ws_size,
                              hipStream_t stream) {
    const float4* o4 = (const float4*)d_in[0];
    const float4* e4 = (const float4*)d_in[1];
    float* out = (float*)d_out;
    float* partial      = (float*)d_ws;                          // 6 MB: [96][128][128]
    float* blockpartial = (float*)d_ws + NPLANE * PLANE_ELEMS;   // + 8 KB

    stageA_pool_kernel<<<NBLK_A, 256, 0, stream>>>(o4, e4, partial);
    spa_reduce_kernel<<<NBLK_RED, 256, 0, stream>>>(partial, blockpartial);
    final_reduce_kernel<<<1, 256, 0, stream>>>(blockpartial, out);
}

// Round 5
// 197.662 us; speedup vs baseline: 1.2105x; 1.0810x over previous
//
#include <hip/hip_runtime.h>

// Problem constants (from reference): org/enh [32,3,512,512] fp32.
#define NB 32
#define NC 3
#define NH 512
#define NW 512
#define PH 128   // NH/4
#define PW 128   // NW/4
#define NPOOL  (NB * PH * PW)     // 524288 pooled elements
#define NPLANE (NB * NC)          // 96 (b,c) planes
#define PLANE_ELEMS (PH * PW)     // 16384 per partial plane
#define NITEMS (NPLANE * PLANE_ELEMS)  // 1,572,864 stage-A work items
#define NBLK_A 2048
#define STRIDE_A (NBLK_A * 256)   // 524288 threads -> exactly 3 items each
#define NBLK_RED (NPOOL / 256)    // 2048

// Native clang vector type: __builtin_nontemporal_load rejects the
// HIP_vector_type struct but accepts ext_vector_type.
typedef float vf4 __attribute__((ext_vector_type(4)));

// Stage A: per-channel fused 4x4 avgpool of (org - enh), software-pipelined.
// Work item = one pooled element (plane, prow, x4): 4 row-strided float4
// loads from each input, horizontal float4 sum = pool width. Each thread
// processes 3 items with a register double-buffer: while computing item k,
// item k+1's 8 loads are already in flight. This forces the compiler to keep
// ~16 loads live (~90 VGPR) instead of re-clustering them into load->wait
// pairs (R3's VGPR=20 showed per-wave MLP ~2 -> 1.5 TB/s plateau).
// Inputs are read exactly once -> nontemporal loads.
__global__ __launch_bounds__(256) void stageA_pool_kernel(
    const vf4* __restrict__ o4, const vf4* __restrict__ e4,
    float* __restrict__ partial)
{
    int item = blockIdx.x * 256 + threadIdx.x;   // 0..524287, 3 grid-stride items

    int base = ((item >> 14) << 16) + (((item >> 7) & 127) << 9) + (item & 127);
    vf4 oc0 = __builtin_nontemporal_load(o4 + base);
    vf4 oc1 = __builtin_nontemporal_load(o4 + base + 128);
    vf4 oc2 = __builtin_nontemporal_load(o4 + base + 256);
    vf4 oc3 = __builtin_nontemporal_load(o4 + base + 384);
    vf4 ec0 = __builtin_nontemporal_load(e4 + base);
    vf4 ec1 = __builtin_nontemporal_load(e4 + base + 128);
    vf4 ec2 = __builtin_nontemporal_load(e4 + base + 256);
    vf4 ec3 = __builtin_nontemporal_load(e4 + base + 384);

#pragma unroll
    for (int it = 0; it < 3; ++it) {
        vf4 on0, on1, on2, on3, en0, en1, en2, en3;
        if (it < 2) {
            int nbase_item = item + STRIDE_A;
            int nbase = ((nbase_item >> 14) << 16) + (((nbase_item >> 7) & 127) << 9)
                      + (nbase_item & 127);
            on0 = __builtin_nontemporal_load(o4 + nbase);
            on1 = __builtin_nontemporal_load(o4 + nbase + 128);
            on2 = __builtin_nontemporal_load(o4 + nbase + 256);
            on3 = __builtin_nontemporal_load(o4 + nbase + 384);
            en0 = __builtin_nontemporal_load(e4 + nbase);
            en1 = __builtin_nontemporal_load(e4 + nbase + 128);
            en2 = __builtin_nontemporal_load(e4 + nbase + 256);
            en3 = __builtin_nontemporal_load(e4 + nbase + 384);
        }

        vf4 d = ((oc0 - ec0) + (oc1 - ec1)) + ((oc2 - ec2) + (oc3 - ec3));
        float v = (d.x + d.y) + (d.z + d.w);
        partial[item] = v * (1.0f / 48.0f);   // /3 channels /16 pool window

        if (it < 2) {
            oc0 = on0; oc1 = on1; oc2 = on2; oc3 = on3;
            ec0 = en0; ec1 = en1; ec2 = en2; ec3 = en3;
            item += STRIDE_A;
        }
    }
}

// Stage B: shift-difference sum-of-squares with inline channel-plane sum.
// pooled[b,y,x] = sum_c partial[(3b+c),y,x]; 6 MB working set, L2/L3-resident.
// Per-block partials to ws (no single-address atomics across XCDs).
__global__ __launch_bounds__(256) void spa_reduce_kernel(
    const float* __restrict__ partial, float* __restrict__ partials_out)
{
    int idx = blockIdx.x * blockDim.x + threadIdx.x;
    int pw = idx & (PW - 1);
    int ph = (idx >> 7) & (PH - 1);
    int b  = idx >> 14;

    const float* p0 = partial + (b * 3 + 0) * PLANE_ELEMS;
    const float* p1 = partial + (b * 3 + 1) * PLANE_ELEMS;
    const float* p2 = partial + (b * 3 + 2) * PLANE_ELEMS;

    #define POOLED(y, x) (p0[(y) * PW + (x)] + p1[(y) * PW + (x)] + p2[(y) * PW + (x)])
    float c = POOLED(ph, pw);
    float l = (pw > 0)      ? POOLED(ph, pw - 1) : 0.f;
    float r = (pw < PW - 1) ? POOLED(ph, pw + 1) : 0.f;
    float u = (ph > 0)      ? POOLED(ph - 1, pw) : 0.f;
    float d = (ph < PH - 1) ? POOLED(ph + 1, pw) : 0.f;
    #undef POOLED

    float dl = c - l, dr = c - r, du = c - u, dd = c - d;
    float s = (dl * dl + dr * dr) + (du * du + dd * dd);

#pragma unroll
    for (int off = 32; off > 0; off >>= 1)
        s += __shfl_down(s, off, 64);

    __shared__ float smem[4];
    int lane = threadIdx.x & 63;
    int wid  = threadIdx.x >> 6;
    if (lane == 0) smem[wid] = s;
    __syncthreads();
    if (threadIdx.x == 0)
        partials_out[blockIdx.x] = (smem[0] + smem[1]) + (smem[2] + smem[3]);
}

// Stage C: single block folds 2048 partials -> final mean, writes d_out.
__global__ __launch_bounds__(256) void final_reduce_kernel(
    const float* __restrict__ partials, float* __restrict__ out)
{
    float s = 0.f;
#pragma unroll
    for (int i = 0; i < NBLK_RED / 256; ++i)
        s += partials[i * 256 + threadIdx.x];

#pragma unroll
    for (int off = 32; off > 0; off >>= 1)
        s += __shfl_down(s, off, 64);

    __shared__ float smem[4];
    int lane = threadIdx.x & 63;
    int wid  = threadIdx.x >> 6;
    if (lane == 0) smem[wid] = s;
    __syncthreads();
    if (threadIdx.x == 0)
        out[0] = ((smem[0] + smem[1]) + (smem[2] + smem[3])) * (1.0f / (float)NPOOL);
}

extern "C" void kernel_launch(void* const* d_in, const int* in_sizes, int n_in,
                              void* d_out, int out_size, void* d_ws, size_t ws_size,
                              hipStream_t stream) {
    const vf4* o4 = (const vf4*)d_in[0];
    const vf4* e4 = (const vf4*)d_in[1];
    float* out = (float*)d_out;
    float* partial      = (float*)d_ws;                 // 6 MB: [96][128][128]
    float* blockpartial = (float*)d_ws + NITEMS;        // + 8 KB

    stageA_pool_kernel<<<NBLK_A, 256, 0, stream>>>(o4, e4, partial);
    spa_reduce_kernel<<<NBLK_RED, 256, 0, stream>>>(partial, blockpartial);
    final_reduce_kernel<<<1, 256, 0, stream>>>(blockpartial, out);
}